// Round 5
// baseline (736.269 us; speedup 1.0000x reference)
//
#include <hip/hip_runtime.h>
#include <math.h>
#include <float.h>

#define D_MODEL 2816
#define N_EXP   64
#define TOPK    8
#define T_TILE  64
#define DC      32
#define NCHUNK  88                  // 2816 / 32
#define SROW    36                  // floats per LDS row (32 data + 4 pad; rows 16B-aligned)
#define SMEM_BYTES 18688
#define TAU     3e-4f               // fixup margin: ~100x worst-case fp32 dot error

// Pass A LDS layout (union):
//   GEMM phase : xs = [0, 9216)      float[64][36]
//                ws = [9216, 18432)  float[64][36]   (scale-folded W)
//   epilogue   : raw  = [0, 16384)     float[64][64]
//                ssqp = [16384, 18432) float[64][8]
//                rn   = [18432, 18688) float[64]

__global__ __launch_bounds__(256, 2)
void router_a(const float* __restrict__ x,
              const float* __restrict__ W,
              const float* __restrict__ scale,
              const float* __restrict__ pes,
              float* __restrict__ out,
              unsigned int* __restrict__ cnt,
              int* __restrict__ list,
              int cap)
{
    __shared__ __align__(16) char smem[SMEM_BYTES];
    float (*xs)[SROW] = (float (*)[SROW])(smem);
    float (*ws)[SROW] = (float (*)[SROW])(smem + 9216);
    float* raw  = (float*)smem;
    float* ssqp = (float*)(smem + 16384);
    float* rn   = (float*)(smem + 18432);

    const int tid  = threadIdx.x;
    const int tb   = blockIdx.x * T_TILE;
    const int lrow = tid >> 3;          // 0..31 (loader row)
    const int kk   = tid & 7;           // 0..7  (loader d-quad)
    const int tg4  = (tid >> 4) << 2;   // compute: token base (4 consecutive)
    const int eg   = tid & 15;          // compute: expert base (strided by 16)

    float acc[4][4] = {};
    float ssq2[2] = {0.f, 0.f};

    for (int c = 0; c < NCHUNK; ++c) {
        const int d0 = c * DC;
        float4 xg[2], wg[2];
        const float4 sc4 = *(const float4*)(scale + d0 + kk * 4);
        #pragma unroll
        for (int r = 0; r < 2; ++r) {
            const int row = r * 32 + lrow;
            xg[r] = *(const float4*)(x + (size_t)(tb + row) * D_MODEL + d0 + kk * 4);
            wg[r] = *(const float4*)(W + (size_t)row * D_MODEL + d0 + kk * 4);
        }
        __syncthreads();   // previous chunk's compute done
        #pragma unroll
        for (int r = 0; r < 2; ++r) {
            const int row = r * 32 + lrow;
            ssq2[r] += xg[r].x * xg[r].x + xg[r].y * xg[r].y
                     + xg[r].z * xg[r].z + xg[r].w * xg[r].w;
            *(float4*)&xs[row][kk * 4] = xg[r];
            float4 wv;
            wv.x = wg[r].x * sc4.x; wv.y = wg[r].y * sc4.y;
            wv.z = wg[r].z * sc4.z; wv.w = wg[r].w * sc4.w;
            *(float4*)&ws[row][kk * 4] = wv;
        }
        __syncthreads();   // tiles ready
        #pragma unroll
        for (int d = 0; d < DC; d += 4) {
            float4 xf[4], wf[4];
            #pragma unroll
            for (int u = 0; u < 4; ++u)
                xf[u] = *(const float4*)&xs[tg4 + u][d];
            #pragma unroll
            for (int v = 0; v < 4; ++v)
                wf[v] = *(const float4*)&ws[eg + 16 * v][d];
            #pragma unroll
            for (int u = 0; u < 4; ++u)
                #pragma unroll
                for (int v = 0; v < 4; ++v) {
                    acc[u][v] = fmaf(xf[u].x, wf[v].x, acc[u][v]);
                    acc[u][v] = fmaf(xf[u].y, wf[v].y, acc[u][v]);
                    acc[u][v] = fmaf(xf[u].z, wf[v].z, acc[u][v]);
                    acc[u][v] = fmaf(xf[u].w, wf[v].w, acc[u][v]);
                }
        }
    }

    __syncthreads();   // last chunk's compute done; tiles now dead

    #pragma unroll
    for (int u = 0; u < 4; ++u)
        #pragma unroll
        for (int v = 0; v < 4; ++v)
            raw[(tg4 + u) * 64 + (eg + 16 * v)] = acc[u][v];
    ssqp[lrow * 8 + kk]        = ssq2[0];
    ssqp[(32 + lrow) * 8 + kk] = ssq2[1];
    __syncthreads();

    if (tid < 64) {
        float s = 0.f;
        #pragma unroll
        for (int j = 0; j < 8; ++j) s += ssqp[tid * 8 + j];
        float v  = s + 0.002816f;               // ssq + D*eps
        float r0 = rsqrtf(v);
        r0 = r0 * (1.5f - 0.5f * v * r0 * r0);  // NR refinement
        rn[tid] = r0;                            // raw*rn == normed score
    }
    __syncthreads();

    // top-k + margin flag + softmax-renorm + scatter
    const int wv = tid >> 6, lane = tid & 63;
    const float pl = pes[lane];
    for (int tk = 0; tk < 16; ++tk) {
        const int t = wv * 16 + tk;
        const float sraw = raw[t * 64 + lane];
        float m = sraw;
        int rank = 0;
        for (int j = 0; j < 64; ++j) {
            float sj = raw[t * 64 + j];
            rank += (sj > sraw) || (sj == sraw && j < lane);
        }
        const bool sel = rank < TOPK;
        float a = sel ?  sraw :  FLT_MAX;   // min over selected   -> rank-8 value
        float b = sel ? -FLT_MAX :  sraw;   // max over unselected -> rank-9 value
        #pragma unroll
        for (int off = 32; off > 0; off >>= 1) {
            m = fmaxf(m, __shfl_xor(m, off));
            a = fminf(a, __shfl_xor(a, off));
            b = fmaxf(b, __shfl_xor(b, off));
        }
        const float rt = rn[t];
        float ex = sel ? __expf((sraw - m) * rt) : 0.f;
        float sum = ex;
        #pragma unroll
        for (int off = 32; off > 0; off >>= 1) sum += __shfl_xor(sum, off);
        out[(size_t)(tb + t) * N_EXP + lane] = sel ? (ex / sum) * pl : 0.f;
        if (lane == 0 && (a - b) < TAU) {
            unsigned int slot = atomicAdd(cnt, 1u);
            if ((int)slot < cap) list[slot] = tb + t;
        }
    }
}

// Pass B: fp64 recompute of flagged tokens (expected ~0.7% of tokens).
__global__ __launch_bounds__(256, 2)
void router_b(const float* __restrict__ x,
              const float* __restrict__ W,
              const float* __restrict__ scale,
              const float* __restrict__ pes,
              float* __restrict__ out,
              const unsigned int* __restrict__ cnt,
              const int* __restrict__ list,
              int cap)
{
    __shared__ double part[256];
    __shared__ double sc[64];
    __shared__ double qsh[4];

    const int tid = threadIdx.x;
    const int e   = tid & 63;       // expert
    const int seg = tid >> 6;       // d-segment: 4 x 704
    int n = (int)*cnt;
    if (n > cap) n = cap;

    for (int i = blockIdx.x; i < n; i += gridDim.x) {
        const int t = list[i];
        const float* xr = x + (size_t)t * D_MODEL;
        const float* wr = W + (size_t)e * D_MODEL;
        double s = 0.0, q = 0.0;
        const int dbeg = seg * 704;
        for (int d = dbeg; d < dbeg + 704; d += 4) {
            float4 xv = *(const float4*)(xr + d);
            float4 wvv = *(const float4*)(wr + d);
            float4 sv = *(const float4*)(scale + d);
            s += (double)xv.x * ((double)sv.x * (double)wvv.x)
               + (double)xv.y * ((double)sv.y * (double)wvv.y)
               + (double)xv.z * ((double)sv.z * (double)wvv.z)
               + (double)xv.w * ((double)sv.w * (double)wvv.w);
            if (e == 0)
                q += (double)xv.x * xv.x + (double)xv.y * xv.y
                   + (double)xv.z * xv.z + (double)xv.w * xv.w;
        }
        part[tid] = s;
        if (e == 0) qsh[seg] = q;
        __syncthreads();
        if (tid < 64)
            sc[tid] = part[tid] + part[tid + 64] + part[tid + 128] + part[tid + 192];
        __syncthreads();
        if (tid < 64) {
            const int lane = tid;
            const double sraw = sc[lane];
            double m = sraw;
            #pragma unroll
            for (int off = 32; off > 0; off >>= 1) {
                double o = __shfl_xor(m, off);
                m = m > o ? m : o;
            }
            int rank = 0;
            for (int j = 0; j < 64; ++j) {
                double sj = sc[j];
                rank += (sj > sraw) || (sj == sraw && j < lane);
            }
            const bool sel = rank < TOPK;
            float ssqf = (float)(qsh[0] + qsh[1] + qsh[2] + qsh[3]);
            float v  = ssqf + 0.002816f;
            float r0 = rsqrtf(v);
            r0 = r0 * (1.5f - 0.5f * v * r0 * r0);
            float ex = sel ? __expf((float)(sraw - m) * r0) : 0.f;
            float sum = ex;
            #pragma unroll
            for (int off = 32; off > 0; off >>= 1) sum += __shfl_xor(sum, off);
            out[(size_t)t * N_EXP + lane] = sel ? (ex / sum) * pes[lane] : 0.f;
        }
        __syncthreads();   // part[]/sc[] reuse safety for next i
    }
}

extern "C" void kernel_launch(void* const* d_in, const int* in_sizes, int n_in,
                              void* d_out, int out_size, void* d_ws, size_t ws_size,
                              hipStream_t stream) {
    const float* x     = (const float*)d_in[0];
    const float* W     = (const float*)d_in[1];
    const float* scale = (const float*)d_in[2];
    const float* pes   = (const float*)d_in[3];
    float* out = (float*)d_out;

    unsigned int* cnt = (unsigned int*)d_ws;
    int* list = (int*)((char*)d_ws + 16);
    long cap_l = ((long)ws_size - 16) / 4;
    int cap = cap_l < 0 ? 0 : (cap_l > 32768 ? 32768 : (int)cap_l);

    const int ntok    = in_sizes[0] / D_MODEL;   // 32768
    const int nblocks = ntok / T_TILE;           // 512

    hipMemsetAsync(d_ws, 0, 16, stream);         // zero the flag counter
    router_a<<<dim3(nblocks), dim3(256), 0, stream>>>(x, W, scale, pes, out, cnt, list, cap);
    router_b<<<dim3(128), dim3(256), 0, stream>>>(x, W, scale, pes, out, cnt, list, cap);
}

// Round 7
// 689.334 us; speedup vs baseline: 1.0681x; 1.0681x over previous
//
#include <hip/hip_runtime.h>
#include <math.h>
#include <float.h>

#define D_MODEL 2816
#define N_EXP   64
#define TOPK    8
#define T_TILE  64
#define DC      32
#define NCHUNK  88                  // 2816 / 32
#define AROW    40                  // bf16 elems per LDS row (32 data + 8 pad; rows 80B, 16B-aligned)
#define TAU_RAW 1e-3f               // raw-score fixup margin; > worst-case split-bf16 error (~5e-4)
#define SMEM_BYTES 20480

typedef __attribute__((ext_vector_type(8))) short short8;   // 8 bf16 (4 VGPRs)
typedef __attribute__((ext_vector_type(4))) float f32x4;    // MFMA acc

// LDS (single-buffer staging, 20480 B):
//   xs_hi [64][40] bf16 @     0   (5120 B)
//   xs_lo [64][40] bf16 @  5120
//   wb_hi [64][40] bf16 @ 10240   (scale-folded W, hi plane)
//   wb_lo [64][40] bf16 @ 15360
// epilogue union (after final barrier):
//   raw  [64][64] f32  @     0   (16384 B)
//   ssqp [64][4]  f32  @ 16384   (1024 B)
//   rn   [64]     f32  @ 17408   (256 B)

__device__ inline ushort bf16_rn(float f) {
    unsigned u = __float_as_uint(f);
    unsigned r = u + 0x7FFFu + ((u >> 16) & 1u);
    return (ushort)(r >> 16);
}

__device__ inline void split4(float4 f, ushort4& h, ushort4& l) {
    ushort h0 = bf16_rn(f.x), h1 = bf16_rn(f.y), h2 = bf16_rn(f.z), h3 = bf16_rn(f.w);
    float r0 = f.x - __uint_as_float((unsigned)h0 << 16);
    float r1 = f.y - __uint_as_float((unsigned)h1 << 16);
    float r2 = f.z - __uint_as_float((unsigned)h2 << 16);
    float r3 = f.w - __uint_as_float((unsigned)h3 << 16);
    h = make_ushort4(h0, h1, h2, h3);
    l = make_ushort4(bf16_rn(r0), bf16_rn(r1), bf16_rn(r2), bf16_rn(r3));
}

__global__ __launch_bounds__(256, 2)
void router_a(const float* __restrict__ x,
              const float* __restrict__ W,
              const float* __restrict__ scale,
              const float* __restrict__ pes,
              float* __restrict__ out,
              unsigned int* __restrict__ cnt,
              int* __restrict__ list,
              int cap)
{
    __shared__ __align__(16) char smem[SMEM_BYTES];
    ushort* xs_hi = (ushort*)smem;            // 64*40 = 2560 elems
    ushort* xs_lo = xs_hi + 2560;
    ushort* wb_hi = xs_lo + 2560;
    ushort* wb_lo = wb_hi + 2560;
    float*  raw   = (float*)smem;
    float*  ssqp  = (float*)(smem + 16384);
    float*  rn    = (float*)(smem + 17408);

    const int tid = threadIdx.x;
    const int tb  = blockIdx.x * T_TILE;
    // staging role: 4 threads per row, fixed across chunks
    const int row = tid >> 2;               // 0..63 (token row / expert row)
    const int q   = tid & 3;                // float4 quad
    const int c0  = 4 * q;                  // cols c0..c0+3 and c0+16..c0+19
    // mfma role
    const int w   = tid >> 6;               // wave 0..3: tokens 16w..16w+15
    const int l   = tid & 63;
    const int lm  = l & 15;
    const int kg  = (l >> 4) * 8;           // k-group offset (bf16 elems)

    const size_t xrow_base = (size_t)(tb + row) * D_MODEL;
    const size_t wrow_base = (size_t)row * D_MODEL;

    f32x4 acc0 = {0.f,0.f,0.f,0.f}, acc1 = {0.f,0.f,0.f,0.f};
    f32x4 acc2 = {0.f,0.f,0.f,0.f}, acc3 = {0.f,0.f,0.f,0.f};
    float sq = 0.f;

    // prologue: issue loads for chunk 0
    float4 xg0 = *(const float4*)(x + xrow_base + c0);
    float4 xg1 = *(const float4*)(x + xrow_base + c0 + 16);
    float4 wg0 = *(const float4*)(W + wrow_base + c0);
    float4 wg1 = *(const float4*)(W + wrow_base + c0 + 16);
    float4 sg0 = *(const float4*)(scale + c0);
    float4 sg1 = *(const float4*)(scale + c0 + 16);

    for (int c = 0; c < NCHUNK; ++c) {
        // ---- convert current chunk (consumes xg/wg/sg) ----
        sq += xg0.x*xg0.x + xg0.y*xg0.y + xg0.z*xg0.z + xg0.w*xg0.w
            + xg1.x*xg1.x + xg1.y*xg1.y + xg1.z*xg1.z + xg1.w*xg1.w;
        ushort4 xh0, xl0, xh1, xl1, wh0, wl0, wh1, wl1;
        split4(xg0, xh0, xl0);
        split4(xg1, xh1, xl1);
        float4 ws0 = make_float4(wg0.x*sg0.x, wg0.y*sg0.y, wg0.z*sg0.z, wg0.w*sg0.w);
        float4 ws1 = make_float4(wg1.x*sg1.x, wg1.y*sg1.y, wg1.z*sg1.z, wg1.w*sg1.w);
        split4(ws0, wh0, wl0);
        split4(ws1, wh1, wl1);

        // ---- prefetch next chunk into regs (hidden under barriers+MFMA) ----
        const int d0n = (c + 1 < NCHUNK ? c + 1 : NCHUNK - 1) * DC;
        xg0 = *(const float4*)(x + xrow_base + d0n + c0);
        xg1 = *(const float4*)(x + xrow_base + d0n + c0 + 16);
        wg0 = *(const float4*)(W + wrow_base + d0n + c0);
        wg1 = *(const float4*)(W + wrow_base + d0n + c0 + 16);
        sg0 = *(const float4*)(scale + d0n + c0);
        sg1 = *(const float4*)(scale + d0n + c0 + 16);

        __syncthreads();   // all waves done reading LDS (prev chunk's MFMA)
        const int rb = row * AROW;
        *(ushort4*)(xs_hi + rb + c0)      = xh0;
        *(ushort4*)(xs_hi + rb + c0 + 16) = xh1;
        *(ushort4*)(xs_lo + rb + c0)      = xl0;
        *(ushort4*)(xs_lo + rb + c0 + 16) = xl1;
        *(ushort4*)(wb_hi + rb + c0)      = wh0;
        *(ushort4*)(wb_hi + rb + c0 + 16) = wh1;
        *(ushort4*)(wb_lo + rb + c0)      = wl0;
        *(ushort4*)(wb_lo + rb + c0 + 16) = wl1;
        __syncthreads();   // tiles ready

        // ---- MFMA: 16 tokens x 64 experts, 3-term bf16 split ----
        const int abase = (16 * w + lm) * AROW + kg;
        short8 ahi = *(const short8*)(xs_hi + abase);
        short8 alo = *(const short8*)(xs_lo + abase);
        {
            const int b0 = (lm) * AROW + kg;
            short8 bhi = *(const short8*)(wb_hi + b0);
            short8 blo = *(const short8*)(wb_lo + b0);
            acc0 = __builtin_amdgcn_mfma_f32_16x16x32_bf16(ahi, bhi, acc0, 0, 0, 0);
            acc0 = __builtin_amdgcn_mfma_f32_16x16x32_bf16(ahi, blo, acc0, 0, 0, 0);
            acc0 = __builtin_amdgcn_mfma_f32_16x16x32_bf16(alo, bhi, acc0, 0, 0, 0);
        }
        {
            const int b1 = (16 + lm) * AROW + kg;
            short8 bhi = *(const short8*)(wb_hi + b1);
            short8 blo = *(const short8*)(wb_lo + b1);
            acc1 = __builtin_amdgcn_mfma_f32_16x16x32_bf16(ahi, bhi, acc1, 0, 0, 0);
            acc1 = __builtin_amdgcn_mfma_f32_16x16x32_bf16(ahi, blo, acc1, 0, 0, 0);
            acc1 = __builtin_amdgcn_mfma_f32_16x16x32_bf16(alo, bhi, acc1, 0, 0, 0);
        }
        {
            const int b2 = (32 + lm) * AROW + kg;
            short8 bhi = *(const short8*)(wb_hi + b2);
            short8 blo = *(const short8*)(wb_lo + b2);
            acc2 = __builtin_amdgcn_mfma_f32_16x16x32_bf16(ahi, bhi, acc2, 0, 0, 0);
            acc2 = __builtin_amdgcn_mfma_f32_16x16x32_bf16(ahi, blo, acc2, 0, 0, 0);
            acc2 = __builtin_amdgcn_mfma_f32_16x16x32_bf16(alo, bhi, acc2, 0, 0, 0);
        }
        {
            const int b3 = (48 + lm) * AROW + kg;
            short8 bhi = *(const short8*)(wb_hi + b3);
            short8 blo = *(const short8*)(wb_lo + b3);
            acc3 = __builtin_amdgcn_mfma_f32_16x16x32_bf16(ahi, bhi, acc3, 0, 0, 0);
            acc3 = __builtin_amdgcn_mfma_f32_16x16x32_bf16(ahi, blo, acc3, 0, 0, 0);
            acc3 = __builtin_amdgcn_mfma_f32_16x16x32_bf16(alo, bhi, acc3, 0, 0, 0);
        }
    }

    __syncthreads();   // staging tiles dead; switch LDS to epilogue layout

    // write raw fp32 logits: D row = (l>>4)*4 + reg (token-within-16), col = lm (expert-within-16)
    {
        const int trow = 16 * w + (l >> 4) * 4;
        #pragma unroll
        for (int r = 0; r < 4; ++r) {
            raw[(trow + r) * 64 +      lm] = acc0[r];
            raw[(trow + r) * 64 + 16 + lm] = acc1[r];
            raw[(trow + r) * 64 + 32 + lm] = acc2[r];
            raw[(trow + r) * 64 + 48 + lm] = acc3[r];
        }
    }
    ssqp[row * 4 + q] = sq;
    __syncthreads();

    if (tid < 64) {
        float s = ssqp[tid*4] + ssqp[tid*4+1] + ssqp[tid*4+2] + ssqp[tid*4+3];
        float v  = s + 0.002816f;               // ssq + D*eps
        float r0 = rsqrtf(v);
        r0 = r0 * (1.5f - 0.5f * v * r0 * r0);  // NR refinement
        rn[tid] = r0;                            // raw*rn == normalized score
    }
    __syncthreads();

    // top-k + margin flag + softmax-renorm + scatter (verified in R5)
    const int wv = tid >> 6, lane = tid & 63;
    const float pl = pes[lane];
    for (int tk = 0; tk < 16; ++tk) {
        const int t = wv * 16 + tk;
        const float sraw = raw[t * 64 + lane];
        float m = sraw;
        int rank = 0;
        for (int j = 0; j < 64; ++j) {
            float sj = raw[t * 64 + j];
            rank += (sj > sraw) || (sj == sraw && j < lane);
        }
        const bool sel = rank < TOPK;
        float a = sel ?  sraw :  FLT_MAX;   // min over selected   -> rank-8 value
        float b = sel ? -FLT_MAX :  sraw;   // max over unselected -> rank-9 value
        #pragma unroll
        for (int off = 32; off > 0; off >>= 1) {
            m = fmaxf(m, __shfl_xor(m, off));
            a = fminf(a, __shfl_xor(a, off));
            b = fmaxf(b, __shfl_xor(b, off));
        }
        const float rt = rn[t];
        float ex = sel ? __expf((sraw - m) * rt) : 0.f;
        float sum = ex;
        #pragma unroll
        for (int off = 32; off > 0; off >>= 1) sum += __shfl_xor(sum, off);
        out[(size_t)(tb + t) * N_EXP + lane] = sel ? (ex / sum) * pl : 0.f;
        if (lane == 0 && (a - b) < TAU_RAW) {
            unsigned int slot = atomicAdd(cnt, 1u);
            if ((int)slot < cap) list[slot] = tb + t;
        }
    }
}

// Pass B: fp64 recompute of flagged tokens (expected ~2.3% = ~750 tokens).
__global__ __launch_bounds__(256, 2)
void router_b(const float* __restrict__ x,
              const float* __restrict__ W,
              const float* __restrict__ scale,
              const float* __restrict__ pes,
              float* __restrict__ out,
              const unsigned int* __restrict__ cnt,
              const int* __restrict__ list,
              int cap)
{
    __shared__ double part[256];
    __shared__ double sc[64];
    __shared__ double qsh[4];

    const int tid = threadIdx.x;
    const int e   = tid & 63;       // expert
    const int seg = tid >> 6;       // d-segment: 4 x 704
    int n = (int)*cnt;
    if (n > cap) n = cap;

    for (int i = blockIdx.x; i < n; i += gridDim.x) {
        const int t = list[i];
        const float* xr = x + (size_t)t * D_MODEL;
        const float* wr = W + (size_t)e * D_MODEL;
        double s = 0.0, qq = 0.0;
        const int dbeg = seg * 704;
        for (int d = dbeg; d < dbeg + 704; d += 4) {
            float4 xv = *(const float4*)(xr + d);
            float4 wvv = *(const float4*)(wr + d);
            float4 sv = *(const float4*)(scale + d);
            s += (double)xv.x * ((double)sv.x * (double)wvv.x)
               + (double)xv.y * ((double)sv.y * (double)wvv.y)
               + (double)xv.z * ((double)sv.z * (double)wvv.z)
               + (double)xv.w * ((double)sv.w * (double)wvv.w);
            if (e == 0)
                qq += (double)xv.x * xv.x + (double)xv.y * xv.y
                    + (double)xv.z * xv.z + (double)xv.w * xv.w;
        }
        part[tid] = s;
        if (e == 0) qsh[seg] = qq;
        __syncthreads();
        if (tid < 64)
            sc[tid] = part[tid] + part[tid + 64] + part[tid + 128] + part[tid + 192];
        __syncthreads();
        if (tid < 64) {
            const int lane = tid;
            const double sraw = sc[lane];
            double m = sraw;
            #pragma unroll
            for (int off = 32; off > 0; off >>= 1) {
                double o = __shfl_xor(m, off);
                m = m > o ? m : o;
            }
            int rank = 0;
            for (int j = 0; j < 64; ++j) {
                double sj = sc[j];
                rank += (sj > sraw) || (sj == sraw && j < lane);
            }
            const bool sel = rank < TOPK;
            float ssqf = (float)(qsh[0] + qsh[1] + qsh[2] + qsh[3]);
            float v  = ssqf + 0.002816f;
            float r0 = rsqrtf(v);
            r0 = r0 * (1.5f - 0.5f * v * r0 * r0);
            float ex = sel ? __expf((float)(sraw - m) * r0) : 0.f;
            float sum = ex;
            #pragma unroll
            for (int off = 32; off > 0; off >>= 1) sum += __shfl_xor(sum, off);
            out[(size_t)t * N_EXP + lane] = sel ? (ex / sum) * pes[lane] : 0.f;
        }
        __syncthreads();   // part[]/sc[] reuse safety for next i
    }
}

extern "C" void kernel_launch(void* const* d_in, const int* in_sizes, int n_in,
                              void* d_out, int out_size, void* d_ws, size_t ws_size,
                              hipStream_t stream) {
    const float* x     = (const float*)d_in[0];
    const float* W     = (const float*)d_in[1];
    const float* scale = (const float*)d_in[2];
    const float* pes   = (const float*)d_in[3];
    float* out = (float*)d_out;

    unsigned int* cnt = (unsigned int*)d_ws;
    int* list = (int*)((char*)d_ws + 16);
    long cap_l = ((long)ws_size - 16) / 4;
    int cap = cap_l < 0 ? 0 : (cap_l > 32768 ? 32768 : (int)cap_l);

    const int ntok    = in_sizes[0] / D_MODEL;   // 32768
    const int nblocks = ntok / T_TILE;           // 512

    hipMemsetAsync(d_ws, 0, 16, stream);         // zero the flag counter
    router_a<<<dim3(nblocks), dim3(256), 0, stream>>>(x, W, scale, pes, out, cnt, list, cap);
    router_b<<<dim3(192), dim3(256), 0, stream>>>(x, W, scale, pes, out, cnt, list, cap);
}